// Round 5
// baseline (463.274 us; speedup 1.0000x reference)
//
#include <hip/hip_runtime.h>
#include <hip/hip_bf16.h>

// out[b,s,o] = scale[o] * dot(x[b,s,:], w_eff[o,:])
//   w_eff = weight + 2.0*(b_w @ a_w);  scale[o] = magnitude[o]/||w_eff[o,:]||
// Phase 1: prep builds w_eff bf16 + scale fp32                 (~10us)
// Phase 2: FUSED GEMM, m97 2-barrier skeleton, but A NEVER TOUCHES LDS:
//          - A fragments are wave-private: loaded global->VGPR as fp32
//            (2x dwordx4 per fragment = the exact 8 floats the MFMA lane
//            needs), converted to bf16 in-register (v_cvt_pk_bf16_f32).
//          - B (w_eff bf16) via global_load_lds width=16 into linear LDS,
//            byte-identical to the round-0 verified path.
//          Per-iter drained LDS traffic drops 3x vs fp32-A-in-LDS (round 4);
//          LDS footprint 8 KB; no x_to_bf16 pass (192 MB + launch saved).

typedef __bf16 bf16x8 __attribute__((ext_vector_type(8)));
typedef float  f32x4  __attribute__((ext_vector_type(4)));

#define D_IN  1024
#define D_OUT 1024
#define M_TOT 32768
#define BM 128
#define BN 128
#define BK 32

__device__ __forceinline__ void gl_lds16(const __bf16* g, __bf16* l) {
    // HBM -> LDS DMA, 16B/lane; LDS dest = wave-uniform base + lane*16.
    __builtin_amdgcn_global_load_lds(
        (const __attribute__((address_space(1))) void*)g,
        (__attribute__((address_space(3))) void*)l,
        16, 0, 0);
}

__global__ void dora_prep(const float* __restrict__ w,
                          const float* __restrict__ a_w,
                          const float* __restrict__ b_w,
                          const float* __restrict__ mag,
                          __bf16* __restrict__ wb,
                          float* __restrict__ scale) {
    const int o = blockIdx.x;
    const int t = threadIdx.x;

    float bw[16];
#pragma unroll
    for (int r = 0; r < 16; ++r) bw[r] = b_w[o * 16 + r];

    float ss = 0.f;
#pragma unroll
    for (int i = 0; i < 4; ++i) {
        const int k = t + i * 256;
        float dot = 0.f;
#pragma unroll
        for (int r = 0; r < 16; ++r) dot = fmaf(bw[r], a_w[r * D_IN + k], dot);
        const float acc = fmaf(2.0f, dot, w[o * D_IN + k]);
        wb[o * D_IN + k] = (__bf16)acc;
        ss = fmaf(acc, acc, ss);
    }
#pragma unroll
    for (int off = 32; off; off >>= 1) ss += __shfl_down(ss, off, 64);
    __shared__ float wsum[4];
    if ((t & 63) == 0) wsum[t >> 6] = ss;
    __syncthreads();
    if (t == 0) {
        const float tot = wsum[0] + wsum[1] + wsum[2] + wsum[3];
        scale[o] = mag[o] / sqrtf(tot);
    }
}

__global__ __launch_bounds__(256) void dora_gemm(const float* __restrict__ x,
                                                 const __bf16* __restrict__ wb,
                                                 const float* __restrict__ scale,
                                                 float* __restrict__ out) {
    __shared__ __bf16 Bs[BN * BK];   // 8 KB, single-buffer, linear row-major

    const int bx = blockIdx.x;
    // XCD-aware swizzle: the 8 bn-siblings sharing one A panel run on ONE
    // XCD's L2 at the same time -> fp32 A re-reads are L2 hits.
    const int xcd = bx & 7;
    const int l   = bx >> 3;
    const int bm  = (xcd * 32 + (l >> 3)) * BM;
    const int bn  = (l & 7) * BN;

    const int t    = threadIdx.x;
    const int lane = t & 63;
    const int wave = t >> 6;
    const int wm = (wave & 1) * 64;
    const int wn = (wave >> 1) * 64;
    const int lm = lane & 15;
    const int lq = lane >> 4;

    // ---- A: direct global->reg. Lane of fragment i needs A[row][lq*8..+7],
    //      row = bm+wm+i*16+lm  (32 contiguous bytes per lane per fragment).
    const float* a0p = x + (size_t)(bm + wm +  0 + lm) * D_IN + lq * 8;
    const float* a1p = x + (size_t)(bm + wm + 16 + lm) * D_IN + lq * 8;
    const float* a2p = x + (size_t)(bm + wm + 32 + lm) * D_IN + lq * 8;
    const float* a3p = x + (size_t)(bm + wm + 48 + lm) * D_IN + lq * 8;

    // ---- B staging (bf16, linear, 2 gl_lds per wave; round-0 pattern) ----
    const int srow0 = wave * 32 + (lane >> 2);
    const int scol  = (lane & 3) * 8;
    const __bf16* bg0 = wb + (size_t)(bn + srow0) * D_IN + scol;
    const __bf16* bg1 = bg0 + 16 * D_IN;
    __bf16* bl0 = Bs + wave * 1024;
    __bf16* bl1 = Bs + wave * 1024 + 512;

    f32x4 acc[4][4] = {};

    for (int kk = 0; kk < D_IN; kk += BK) {
        // Issue all loads up front; the barrier's vmcnt drain covers them.
        gl_lds16(bg0 + kk, bl0);
        gl_lds16(bg1 + kk, bl1);
        const f32x4 al0 = *(const f32x4*)(a0p + kk);
        const f32x4 ah0 = *(const f32x4*)(a0p + kk + 4);
        const f32x4 al1 = *(const f32x4*)(a1p + kk);
        const f32x4 ah1 = *(const f32x4*)(a1p + kk + 4);
        const f32x4 al2 = *(const f32x4*)(a2p + kk);
        const f32x4 ah2 = *(const f32x4*)(a2p + kk + 4);
        const f32x4 al3 = *(const f32x4*)(a3p + kk);
        const f32x4 ah3 = *(const f32x4*)(a3p + kk + 4);
        __syncthreads();   // B tile resident (and A regs landed)

        bf16x8 af[4];
        {
            bf16x8 a8;
            a8 = (bf16x8){ (__bf16)al0.x, (__bf16)al0.y, (__bf16)al0.z, (__bf16)al0.w,
                           (__bf16)ah0.x, (__bf16)ah0.y, (__bf16)ah0.z, (__bf16)ah0.w };
            af[0] = a8;
            a8 = (bf16x8){ (__bf16)al1.x, (__bf16)al1.y, (__bf16)al1.z, (__bf16)al1.w,
                           (__bf16)ah1.x, (__bf16)ah1.y, (__bf16)ah1.z, (__bf16)ah1.w };
            af[1] = a8;
            a8 = (bf16x8){ (__bf16)al2.x, (__bf16)al2.y, (__bf16)al2.z, (__bf16)al2.w,
                           (__bf16)ah2.x, (__bf16)ah2.y, (__bf16)ah2.z, (__bf16)ah2.w };
            af[2] = a8;
            a8 = (bf16x8){ (__bf16)al3.x, (__bf16)al3.y, (__bf16)al3.z, (__bf16)al3.w,
                           (__bf16)ah3.x, (__bf16)ah3.y, (__bf16)ah3.z, (__bf16)ah3.w };
            af[3] = a8;
        }

        bf16x8 bfr[4];
#pragma unroll
        for (int j = 0; j < 4; ++j)
            bfr[j] = *(const bf16x8*)(&Bs[(wn + j * 16 + lm) * BK + lq * 8]);

#pragma unroll
        for (int i = 0; i < 4; ++i)
#pragma unroll
            for (int j = 0; j < 4; ++j)
                acc[i][j] = __builtin_amdgcn_mfma_f32_16x16x32_bf16(af[i], bfr[j], acc[i][j], 0, 0, 0);
        __syncthreads();   // all B reads done before next-iter overwrite
    }

    // Epilogue: C/D map col = lane&15 (n), row = (lane>>4)*4 + reg (m)
#pragma unroll
    for (int j = 0; j < 4; ++j) {
        const int n = bn + wn + j * 16 + lm;
        const float sc = scale[n];
#pragma unroll
        for (int i = 0; i < 4; ++i) {
            const int m = bm + wm + i * 16 + lq * 4;
#pragma unroll
            for (int r = 0; r < 4; ++r) {
                out[(size_t)(m + r) * D_OUT + n] = acc[i][j][r] * sc;
            }
        }
    }
}

extern "C" void kernel_launch(void* const* d_in, const int* in_sizes, int n_in,
                              void* d_out, int out_size, void* d_ws, size_t ws_size,
                              hipStream_t stream) {
    const float* x    = (const float*)d_in[0];   // [4,8192,1024] fp32
    const float* w    = (const float*)d_in[1];   // [1024,1024]
    const float* a_w  = (const float*)d_in[2];   // [16,1024]
    const float* b_w  = (const float*)d_in[3];   // [1024,16]
    const float* mag  = (const float*)d_in[4];   // [1,1024]
    float* out = (float*)d_out;                  // [4,8192,1024] fp32

    __bf16* wb   = (__bf16*)d_ws;                                    // 2 MB
    float* scale = (float*)((char*)d_ws + (size_t)D_OUT * D_IN * 2); // 4 KB

    dora_prep<<<D_OUT, 256, 0, stream>>>(w, a_w, b_w, mag, wb, scale);

    const int grid = (M_TOT / BM) * (D_OUT / BN);  // 2048
    dora_gemm<<<grid, 256, 0, stream>>>(x, wb, scale, out);
}

// Round 6
// 320.136 us; speedup vs baseline: 1.4471x; 1.4471x over previous
//
#include <hip/hip_runtime.h>
#include <hip/hip_bf16.h>

// out[b,s,o] = scale[o] * dot(x[b,s,:], w_eff[o,:])
//   w_eff = weight + 2.0*(b_w @ a_w);  scale[o] = magnitude[o]/||w_eff[o,:]||
// Structure (re-anchored on the verified round-0 configuration):
// Phase 0: x fp32 -> bf16, grid-stride 2048 blocks, 16 elem/thread
//          (192 MB stream; tuned toward the 6.3 TB/s ceiling).
// Phase 1: prep builds w_eff bf16 + scale fp32                  (~4us)
// Phase 2: m97-style bf16 MFMA GEMM (verified 94us / 727 TF):
//          global_load_lds width=16 staging, single-buffer, 2 barriers,
//          XCD-aware block swizzle. Byte-identical to the round-0 GEMM.
// Fusion of the cvt into the GEMM was tried 3 ways (reg-stage+ds_write,
// fp32-in-LDS, A-in-reg): all lose — the 2-barrier loop is drain-bound and
// fp32 A inflates exactly the drained quantity. Keep the passes separate.

typedef __bf16 bf16x8 __attribute__((ext_vector_type(8)));
typedef float  f32x4  __attribute__((ext_vector_type(4)));

#define D_IN  1024
#define D_OUT 1024
#define M_TOT 32768
#define BM 128
#define BN 128
#define BK 32

__device__ __forceinline__ void gl_lds16(const __bf16* g, __bf16* l) {
    // HBM -> LDS DMA, 16B per lane; LDS dest = wave-uniform base + lane*16.
    __builtin_amdgcn_global_load_lds(
        (const __attribute__((address_space(1))) void*)g,
        (__attribute__((address_space(3))) void*)l,
        16, 0, 0);
}

__global__ __launch_bounds__(256) void x_to_bf16(const float* __restrict__ x,
                                                 __bf16* __restrict__ xb) {
    // Grid-stride stream: 16 floats per thread per iter (2x dwordx4 in,
    // 2x dwordx4 out). 2048 blocks x 256 thr -> 4 iters over 33.5M elems.
    const size_t stride = (size_t)gridDim.x * blockDim.x;
    const size_t n16 = (size_t)M_TOT * D_IN / 16;
    for (size_t i = (size_t)blockIdx.x * blockDim.x + threadIdx.x; i < n16;
         i += stride) {
        const size_t base = i * 16;
        const float4 v0 = *(const float4*)(x + base);
        const float4 v1 = *(const float4*)(x + base + 4);
        const float4 v2 = *(const float4*)(x + base + 8);
        const float4 v3 = *(const float4*)(x + base + 12);
        bf16x8 p0 = { (__bf16)v0.x, (__bf16)v0.y, (__bf16)v0.z, (__bf16)v0.w,
                      (__bf16)v1.x, (__bf16)v1.y, (__bf16)v1.z, (__bf16)v1.w };
        bf16x8 p1 = { (__bf16)v2.x, (__bf16)v2.y, (__bf16)v2.z, (__bf16)v2.w,
                      (__bf16)v3.x, (__bf16)v3.y, (__bf16)v3.z, (__bf16)v3.w };
        *(bf16x8*)(xb + base)     = p0;
        *(bf16x8*)(xb + base + 8) = p1;
    }
}

__global__ void dora_prep(const float* __restrict__ w,
                          const float* __restrict__ a_w,
                          const float* __restrict__ b_w,
                          const float* __restrict__ mag,
                          __bf16* __restrict__ wb,
                          float* __restrict__ scale) {
    const int o = blockIdx.x;
    const int t = threadIdx.x;

    float bw[16];
#pragma unroll
    for (int r = 0; r < 16; ++r) bw[r] = b_w[o * 16 + r];

    float ss = 0.f;
#pragma unroll
    for (int i = 0; i < 4; ++i) {
        const int k = t + i * 256;
        float dot = 0.f;
#pragma unroll
        for (int r = 0; r < 16; ++r) dot = fmaf(bw[r], a_w[r * D_IN + k], dot);
        const float acc = fmaf(2.0f, dot, w[o * D_IN + k]);
        wb[o * D_IN + k] = (__bf16)acc;
        ss = fmaf(acc, acc, ss);
    }
#pragma unroll
    for (int off = 32; off; off >>= 1) ss += __shfl_down(ss, off, 64);
    __shared__ float wsum[4];
    if ((t & 63) == 0) wsum[t >> 6] = ss;
    __syncthreads();
    if (t == 0) {
        const float tot = wsum[0] + wsum[1] + wsum[2] + wsum[3];
        scale[o] = mag[o] / sqrtf(tot);
    }
}

__global__ void dora_gemm(const __bf16* __restrict__ xb,
                          const __bf16* __restrict__ wb,
                          const float* __restrict__ scale,
                          float* __restrict__ out) {
    // Unpadded contiguous tiles (global_load_lds requires lane-contiguous dest).
    __shared__ __bf16 As[BM * BK];   // 8 KB, row-major [128][32]
    __shared__ __bf16 Bs[BN * BK];   // 8 KB

    const int bx = blockIdx.x;
    // XCD-aware swizzle: consecutive blockIdx round-robin across 8 XCDs
    // (xcd = bx & 7). Give each XCD 32 contiguous bm tiles, bn fastest, so the
    // 8 blocks sharing an A tile sit on ONE XCD's L2 at the same time.
    const int xcd = bx & 7;
    const int l   = bx >> 3;
    const int bm  = (xcd * 32 + (l >> 3)) * BM;
    const int bn  = (l & 7) * BN;

    const int t  = threadIdx.x;
    const int lane = t & 63;
    const int wave = t >> 6;
    const int wm = (wave & 1) * 64;
    const int wn = (wave >> 1) * 64;
    const int lm = lane & 15;
    const int lq = lane >> 4;

    f32x4 acc[4][4] = {};

    // Staging: per K-iter each 8KB tile = 8 chunks of 1KB (16 rows x 64B).
    // Wave w stages chunks {2w, 2w+1}. Lane i -> row i>>2, col (i&3)*16B;
    // LDS byte offset 16*i (lane-contiguous).
    const int srow0 = wave * 32 + (lane >> 2);
    const int scol  = (lane & 3) * 8;
    const __bf16* ag0 = xb + (size_t)(bm + srow0) * D_IN + scol;
    const __bf16* ag1 = ag0 + 16 * D_IN;
    const __bf16* bg0 = wb + (size_t)(bn + srow0) * D_IN + scol;
    const __bf16* bg1 = bg0 + 16 * D_IN;
    __bf16* al0 = As + wave * 1024;
    __bf16* al1 = As + wave * 1024 + 512;
    __bf16* bl0 = Bs + wave * 1024;
    __bf16* bl1 = Bs + wave * 1024 + 512;

    for (int kk = 0; kk < D_IN; kk += BK) {
        gl_lds16(ag0 + kk, al0);
        gl_lds16(ag1 + kk, al1);
        gl_lds16(bg0 + kk, bl0);
        gl_lds16(bg1 + kk, bl1);
        __syncthreads();

        bf16x8 af[4], bfr[4];
#pragma unroll
        for (int i = 0; i < 4; ++i)
            af[i] = *(const bf16x8*)(&As[(wm + i * 16 + lm) * BK + lq * 8]);
#pragma unroll
        for (int i = 0; i < 4; ++i)
            bfr[i] = *(const bf16x8*)(&Bs[(wn + i * 16 + lm) * BK + lq * 8]);

#pragma unroll
        for (int i = 0; i < 4; ++i)
#pragma unroll
            for (int j = 0; j < 4; ++j)
                acc[i][j] = __builtin_amdgcn_mfma_f32_16x16x32_bf16(af[i], bfr[j], acc[i][j], 0, 0, 0);
        __syncthreads();
    }

    // C/D map: col = lane&15 (n), row = (lane>>4)*4 + reg (m)
#pragma unroll
    for (int j = 0; j < 4; ++j) {
        const int n = bn + wn + j * 16 + lm;
        const float sc = scale[n];
#pragma unroll
        for (int i = 0; i < 4; ++i) {
            const int m = bm + wm + i * 16 + lq * 4;
#pragma unroll
            for (int r = 0; r < 4; ++r) {
                out[(size_t)(m + r) * D_OUT + n] = acc[i][j][r] * sc;
            }
        }
    }
}

extern "C" void kernel_launch(void* const* d_in, const int* in_sizes, int n_in,
                              void* d_out, int out_size, void* d_ws, size_t ws_size,
                              hipStream_t stream) {
    const float* x    = (const float*)d_in[0];   // [4,8192,1024] fp32
    const float* w    = (const float*)d_in[1];   // [1024,1024]
    const float* a_w  = (const float*)d_in[2];   // [16,1024]
    const float* b_w  = (const float*)d_in[3];   // [1024,16]
    const float* mag  = (const float*)d_in[4];   // [1,1024]
    float* out = (float*)d_out;                  // [4,8192,1024] fp32

    __bf16* xb   = (__bf16*)d_ws;                                      // 64 MB
    __bf16* wb   = (__bf16*)((char*)d_ws + (size_t)M_TOT * D_IN * 2);  // 2 MB
    float* scale = (float*)((char*)wb + (size_t)D_OUT * D_IN * 2);     // 4 KB

    x_to_bf16<<<2048, 256, 0, stream>>>(x, xb);
    dora_prep<<<D_OUT, 256, 0, stream>>>(w, a_w, b_w, mag, wb, scale);

    const int grid = (M_TOT / BM) * (D_OUT / BN);  // 2048
    dora_gemm<<<grid, 256, 0, stream>>>(xb, wb, scale, out);
}